// Round 17
// baseline (1489.117 us; speedup 1.0000x reference)
//
#include <hip/hip_runtime.h>
#include <cstdint>
#include <cstddef>

#define NREL 8
#define NG 64
#define LN_EPS 1e-5f
#define NEG_SLOPE 0.01f

typedef unsigned short u16;
typedef short bf16x8 __attribute__((ext_vector_type(8)));
typedef float f32x4 __attribute__((ext_vector_type(4)));

static __device__ __forceinline__ float b2f(u16 h) {
  return __uint_as_float(((unsigned)h) << 16);
}
static __device__ __forceinline__ u16 f2b(float f) {
  unsigned u = __float_as_uint(f);
  u += 0x7fffu + ((u >> 16) & 1u);   // RNE
  return (u16)(u >> 16);
}
static __device__ __forceinline__ void upadd8(uint4 v, float* a) {
  a[0] += b2f((u16)(v.x & 0xffff)); a[1] += b2f((u16)(v.x >> 16));
  a[2] += b2f((u16)(v.y & 0xffff)); a[3] += b2f((u16)(v.y >> 16));
  a[4] += b2f((u16)(v.z & 0xffff)); a[5] += b2f((u16)(v.z >> 16));
  a[6] += b2f((u16)(v.w & 0xffff)); a[7] += b2f((u16)(v.w >> 16));
}
static __device__ __forceinline__ uint4 pack8(const float* a) {
  uint4 o;
  o.x = (unsigned)f2b(a[0]) | ((unsigned)f2b(a[1]) << 16);
  o.y = (unsigned)f2b(a[2]) | ((unsigned)f2b(a[3]) << 16);
  o.z = (unsigned)f2b(a[4]) | ((unsigned)f2b(a[5]) << 16);
  o.w = (unsigned)f2b(a[6]) | ((unsigned)f2b(a[7]) << 16);
  return o;
}

// ------------------------------------------------------------------
// setup kernels
// ------------------------------------------------------------------
__global__ void count_edges_k(const int* __restrict__ dst, const int* __restrict__ et,
                              int* __restrict__ cnt, int E) {
  int e = blockIdx.x * blockDim.x + threadIdx.x;
  if (e < E) atomicAdd(&cnt[dst[e] * NREL + et[e]], 1);
}

__global__ void graph_inv_k(const int* __restrict__ batch, float* __restrict__ ginv, int N) {
  int g = threadIdx.x;
  if (g >= NG) return;
  int a, b;
  { int l = 0, h = N; while (l < h) { int m = (l + h) >> 1; if (batch[m] < g) l = m + 1; else h = m; } a = l; }
  { int l = 0, h = N; while (l < h) { int m = (l + h) >> 1; if (batch[m] < g + 1) l = m + 1; else h = m; } b = l; }
  ginv[g] = 1.0f / fmaxf((float)(b - a), 1.0f);
}

#define SCAN_B 256
#define SCAN_I 4

__global__ void scan1_k(const int* __restrict__ in, int* __restrict__ out,
                        int* __restrict__ bsum, int n) {
  __shared__ int sh[SCAN_B];
  int b0 = blockIdx.x * (SCAN_B * SCAN_I);
  int t = threadIdx.x;
  int v[SCAN_I]; int s = 0;
#pragma unroll
  for (int i = 0; i < SCAN_I; ++i) {
    int idx = b0 + t * SCAN_I + i;
    v[i] = idx < n ? in[idx] : 0;
    s += v[i];
  }
  sh[t] = s; __syncthreads();
  for (int off = 1; off < SCAN_B; off <<= 1) {
    int x = (t >= off) ? sh[t - off] : 0; __syncthreads();
    sh[t] += x; __syncthreads();
  }
  int excl = sh[t] - s;
  if (t == SCAN_B - 1) bsum[blockIdx.x] = sh[t];
  int run = excl;
#pragma unroll
  for (int i = 0; i < SCAN_I; ++i) {
    int idx = b0 + t * SCAN_I + i;
    if (idx < n) out[idx] = run;
    run += v[i];
  }
}

__global__ void scan2_k(int* __restrict__ bsum, int nb) {
  __shared__ int sh[1024];
  int t = threadIdx.x;
  int v = t < nb ? bsum[t] : 0;
  sh[t] = v; __syncthreads();
  for (int off = 1; off < 1024; off <<= 1) {
    int x = (t >= off) ? sh[t - off] : 0; __syncthreads();
    sh[t] += x; __syncthreads();
  }
  if (t < nb) bsum[t] = sh[t] - v;
}

__global__ void scan3_k(int* __restrict__ out, const int* __restrict__ bsum, int n, int total) {
  int idx = blockIdx.x * blockDim.x + threadIdx.x;
  if (idx < n) out[idx] += bsum[idx / (SCAN_B * SCAN_I)];
  if (idx == 0) out[n] = total;
}

// scatter edges into CSR order; ONE 16B store per edge:
// earray[p] = {src, batch[src]*8+etype, bits(1/seg_len), 0}
__global__ void scatter_k(const int* __restrict__ src, const int* __restrict__ dst,
                          const int* __restrict__ et, const int* __restrict__ batch,
                          const int* __restrict__ cnt, int* __restrict__ cursor,
                          int4* __restrict__ earray, int E) {
  int e = blockIdx.x * blockDim.x + threadIdx.x;
  if (e >= E) return;
  int s = src[e];
  int r = et[e];
  int key = dst[e] * NREL + r;
  float w = 1.0f / (float)cnt[key];
  int p = atomicAdd(&cursor[key], 1);
  earray[p] = make_int4(s, batch[s] * NREL + r, __float_as_int(w), 0);
}

// ------------------------------------------------------------------
// weight prep: transpose-cast f32 source block -> bf16 pool [D][ldout]
// ------------------------------------------------------------------
__global__ void wtrans_k(const float* __restrict__ in, u16* __restrict__ out,
                         int rstride, int coff, int D, int ldout) {
  __shared__ float tl[32][33];
  int c0 = blockIdx.x * 32;
  int d0 = blockIdx.y * 32;
  int t = threadIdx.x;
  int r = c0 >> 7;
  int rowbase = r * rstride + (c0 & 127) + coff;
#pragma unroll
  for (int i = 0; i < 4; ++i) {
    int cl = (t >> 5) + i * 8;
    tl[cl][t & 31] = in[(size_t)(rowbase + cl) * D + d0 + (t & 31)];
  }
  __syncthreads();
#pragma unroll
  for (int i = 0; i < 4; ++i) {
    int dl = (t >> 5) + i * 8;
    out[(size_t)(d0 + dl) * ldout + c0 + (t & 31)] = f2b(tl[t & 31][dl]);
  }
}

// MHA fold: wc[n][j] = sum_m Wo[n][m]*Wv[m][j] (bf16); bc[n] = Wo[n]·bv + bo[n]
__global__ void wcfold_k(const float* __restrict__ wo, const float* __restrict__ wv,
                         const float* __restrict__ bv, const float* __restrict__ bo,
                         u16* __restrict__ wc, float* __restrict__ bc) {
  __shared__ float worow[256];
  int n = blockIdx.x, j = threadIdx.x;
  worow[j] = wo[n * 256 + j];
  __syncthreads();
  float s = 0.f;
#pragma unroll 4
  for (int m = 0; m < 256; ++m) s += worow[m] * wv[(size_t)m * 256 + j];
  wc[(size_t)n * 256 + j] = f2b(s);
  if (j == 0) {
    float b = bo[n];
    for (int m = 0; m < 256; ++m) b += worow[m] * bv[m];
    bc[n] = b;
  }
}

// plain cast f32 -> bf16 (n multiple of 4)
__global__ void castf_k(const float* __restrict__ in, u16* __restrict__ out, int n) {
  int i = (blockIdx.x * blockDim.x + threadIdx.x) * 4;
  if (i >= n) return;
  float4 v = *(const float4*)(in + i);
  ushort4 o;
  o.x = f2b(v.x); o.y = f2b(v.y); o.z = f2b(v.z); o.w = f2b(v.w);
  *(ushort4*)(out + i) = o;
}

// ------------------------------------------------------------------
// CSR segment aggregation, bf16 in/out, normal stores (L2/LLC-hot for GEMM).
// S[seg][0..128) = (1/max(len,1)) * sum_{e in seg} x[earray[e].x][0..128)
// 16 lanes x 16B per segment; edge loop 4-way unrolled for latency overlap
// ------------------------------------------------------------------
__global__ void agg_csr_b(const int4* __restrict__ earray, const int* __restrict__ off,
                          const u16* __restrict__ xin, int xstride,
                          u16* __restrict__ S, int NSEG) {
  int gid = blockIdx.x * blockDim.x + threadIdx.x;
  int seg = gid >> 4;
  int lane = gid & 15;
  if (seg >= NSEG) return;
  int a = off[seg], b = off[seg + 1];
  float inv = 1.0f / fmaxf((float)(b - a), 1.0f);
  float ac[8] = {0.f, 0.f, 0.f, 0.f, 0.f, 0.f, 0.f, 0.f};
  int e = a;
  for (; e + 3 < b; e += 4) {
    int s0 = earray[e].x, s1 = earray[e + 1].x, s2 = earray[e + 2].x, s3 = earray[e + 3].x;
    uint4 v0 = *(const uint4*)(xin + (size_t)s0 * xstride + lane * 8);
    uint4 v1 = *(const uint4*)(xin + (size_t)s1 * xstride + lane * 8);
    uint4 v2 = *(const uint4*)(xin + (size_t)s2 * xstride + lane * 8);
    uint4 v3 = *(const uint4*)(xin + (size_t)s3 * xstride + lane * 8);
    upadd8(v0, ac); upadd8(v1, ac); upadd8(v2, ac); upadd8(v3, ac);
  }
  for (; e < b; ++e) {
    uint4 v = *(const uint4*)(xin + (size_t)earray[e].x * xstride + lane * 8);
    upadd8(v, ac);
  }
#pragma unroll
  for (int i = 0; i < 8; ++i) ac[i] *= inv;
  *(uint4*)(S + (size_t)seg * 128 + lane * 8) = pack8(ac);
}

// ------------------------------------------------------------------
// pooled bf16 MFMA GEMM with REGISTER DOUBLE-BUFFERING:
// next K-tile's A/B fragments are prefetched into registers right after the
// LDS-write barrier, so global-load latency overlaps the 32 MFMAs of the
// current tile (the kernel is latency-bound at 26% occupancy: grid=391).
// C[m,n] (+)= sum_k A[m,k]*B[n,k]; BM=128, BN=WN*64, BK=64, WN*2 waves.
// A virtual concat: [0,Kagg) from Sa ([M][Kagg]); then 128-col groups from
// dir0/dir1 (row strides ds0/ds1; (k-Kagg)&128 picks dir1). B: [Nout][ldb].
// ACTMODE: 0 none, 1 all cols, 2 only cols with (n&128)==0
// ------------------------------------------------------------------
template<int WN, bool ACC, int ACTMODE>
__global__ __launch_bounds__(WN * 128)
void gemm_pool(const u16* __restrict__ Sa, int Kagg,
               const u16* __restrict__ dir0, int ds0,
               const u16* __restrict__ dir1, int ds1,
               const u16* __restrict__ Bp, int ldb,
               const float* __restrict__ bias, u16* __restrict__ C,
               int M, int N, int Ktot) {
  constexpr int BN = WN * 64;
  constexpr int CPT = 64 / WN;
  constexpr int SLOTS = CPT / 8;
  __shared__ u16 As[128 * 64];
  __shared__ u16 Bs[BN * 64];
  int bm = blockIdx.x * 128;
  int bn = blockIdx.y * BN;
  int t = threadIdx.x;
  int lane = t & 63;
  int wid = t >> 6;
  int wm = (wid / WN) * 64, wn = (wid % WN) * 64;
  int l15 = lane & 15, l4 = lane >> 4;

  f32x4 acc[4][4];
#pragma unroll
  for (int i = 0; i < 4; ++i)
#pragma unroll
    for (int j = 0; j < 4; ++j)
      acc[i][j] = (f32x4){0.f, 0.f, 0.f, 0.f};

  int srow = t / WN, sub = t % WN;
  int arow = bm + srow;
  int swz = srow & 7;
  int srB = t >> 1;
  int sB32 = (t & 1) * 32;
  int swzB = srB & 7;
  const u16* bpp = Bp + (size_t)(bn + srB) * ldb + sB32;

  auto aptr = [&](int k0) -> const u16* {
    if (k0 < Kagg) return Sa + (size_t)arow * Kagg + k0 + sub * CPT;
    int kd = k0 - Kagg;
    return ((kd & 128) ? (dir1 + (size_t)arow * ds1 + (kd & 127))
                       : (dir0 + (size_t)arow * ds0 + (kd & 127))) + sub * CPT;
  };

  uint4 ra[SLOTS], rb[4];
  // prologue: load K-tile 0 into registers
  {
    const u16* ap = aptr(0);
#pragma unroll
    for (int s = 0; s < SLOTS; ++s) {
      uint4 v = make_uint4(0, 0, 0, 0);
      if (arow < M) v = *(const uint4*)(ap + s * 8);
      ra[s] = v;
    }
#pragma unroll
    for (int i = 0; i < 4; ++i) rb[i] = *(const uint4*)(bpp + i * 8);
  }

  for (int k0 = 0; k0 < Ktot; k0 += 64) {
    __syncthreads();
#pragma unroll
    for (int s = 0; s < SLOTS; ++s) {
      int slot = (sub * SLOTS + s) ^ swz;
      *(uint4*)&As[srow * 64 + slot * 8] = ra[s];
    }
#pragma unroll
    for (int i = 0; i < 4; ++i)
      *(uint4*)&Bs[srB * 64 + ((((t & 1) * 4 + i) ^ swzB) << 3)] = rb[i];
    __syncthreads();

    // prefetch next K-tile (overlaps with MFMA below)
    int kn = k0 + 64;
    if (kn < Ktot) {
      const u16* ap = aptr(kn);
#pragma unroll
      for (int s = 0; s < SLOTS; ++s) {
        uint4 v = make_uint4(0, 0, 0, 0);
        if (arow < M) v = *(const uint4*)(ap + s * 8);
        ra[s] = v;
      }
#pragma unroll
      for (int i = 0; i < 4; ++i) rb[i] = *(const uint4*)(bpp + kn + i * 8);
    }

#pragma unroll
    for (int kk = 0; kk < 2; ++kk) {
      bf16x8 aF[4], bF[4];
#pragma unroll
      for (int mi = 0; mi < 4; ++mi) {
        int row = wm + mi * 16 + l15;
        int slot = (kk * 4 + l4) ^ (row & 7);
        aF[mi] = *(const bf16x8*)&As[row * 64 + slot * 8];
      }
#pragma unroll
      for (int ni = 0; ni < 4; ++ni) {
        int row = wn + ni * 16 + l15;
        int slot = (kk * 4 + l4) ^ (row & 7);
        bF[ni] = *(const bf16x8*)&Bs[row * 64 + slot * 8];
      }
#pragma unroll
      for (int mi = 0; mi < 4; ++mi)
#pragma unroll
        for (int ni = 0; ni < 4; ++ni)
          acc[mi][ni] = __builtin_amdgcn_mfma_f32_16x16x32_bf16(
              bF[ni], aF[mi], acc[mi][ni], 0, 0, 0);
    }
  }

#pragma unroll
  for (int mi = 0; mi < 4; ++mi) {
    int m = bm + wm + mi * 16 + l15;
    if (m >= M) continue;
#pragma unroll
    for (int ni = 0; ni < 4; ++ni) {
      int nb = bn + wn + ni * 16 + l4 * 4;
      float v0 = acc[mi][ni][0], v1 = acc[mi][ni][1];
      float v2 = acc[mi][ni][2], v3 = acc[mi][ni][3];
      u16* cp = C + (size_t)m * N + nb;
      if (ACC) {
        ushort4 o = *(const ushort4*)cp;
        v0 += b2f(o.x); v1 += b2f(o.y); v2 += b2f(o.z); v3 += b2f(o.w);
      } else {
        float4 bv = *(const float4*)(bias + nb);
        v0 += bv.x; v1 += bv.y; v2 += bv.z; v3 += bv.w;
      }
      bool da = (ACTMODE == 1) || (ACTMODE == 2 && !(nb & 128));
      if (da) {
        v0 = v0 > 0.f ? v0 : NEG_SLOPE * v0;
        v1 = v1 > 0.f ? v1 : NEG_SLOPE * v1;
        v2 = v2 > 0.f ? v2 : NEG_SLOPE * v2;
        v3 = v3 > 0.f ? v3 : NEG_SLOPE * v3;
      }
      ushort4 o;
      o.x = f2b(v0); o.y = f2b(v1); o.z = f2b(v2); o.w = f2b(v3);
      *(ushort4*)cp = o;
    }
  }
}

// ------------------------------------------------------------------
// GEMM + residual + LayerNorm fused (encoder): out = LN(A@B^T + bias + res)
// A [M][256], B [256][256], BM=128, BN=256 (full row in block), 512 thr.
// ------------------------------------------------------------------
__global__ __launch_bounds__(512)
void gemm_ln(const u16* __restrict__ A, const u16* __restrict__ Bp,
             const float* __restrict__ bias, const u16* __restrict__ res,
             const float* __restrict__ gp, const float* __restrict__ bpar,
             u16* __restrict__ out, int M) {
  __shared__ u16 As[128 * 64];
  __shared__ u16 Bs[256 * 64];
  __shared__ float2 part[4][128];
  int bm = blockIdx.x * 128;
  int t = threadIdx.x;
  int lane = t & 63;
  int wid = t >> 6;
  int wm = (wid >> 2) * 64, wn = (wid & 3) * 64;
  int l15 = lane & 15, l4 = lane >> 4;

  f32x4 acc[4][4];
#pragma unroll
  for (int i = 0; i < 4; ++i)
#pragma unroll
    for (int j = 0; j < 4; ++j)
      acc[i][j] = (f32x4){0.f, 0.f, 0.f, 0.f};

  int srow = t >> 2, sub = t & 3;
  int arow = bm + srow;
  int swz = srow & 7;
  int srB = t >> 1;
  int sB32 = (t & 1) * 32;
  int swzB = srB & 7;
  const u16* bpp = Bp + (size_t)srB * 256 + sB32;

  for (int k0 = 0; k0 < 256; k0 += 64) {
    __syncthreads();
    {
      const u16* ap = A + (size_t)arow * 256 + k0 + sub * 16;
#pragma unroll
      for (int s = 0; s < 2; ++s) {
        uint4 v = make_uint4(0, 0, 0, 0);
        if (arow < M) v = *(const uint4*)(ap + s * 8);
        int slot = (sub * 2 + s) ^ swz;
        *(uint4*)&As[srow * 64 + slot * 8] = v;
      }
    }
#pragma unroll
    for (int i = 0; i < 4; ++i) {
      uint4 v = *(const uint4*)(bpp + k0 + i * 8);
      *(uint4*)&Bs[srB * 64 + ((((t & 1) * 4 + i) ^ swzB) << 3)] = v;
    }
    __syncthreads();

#pragma unroll
    for (int kk = 0; kk < 2; ++kk) {
      bf16x8 aF[4], bF[4];
#pragma unroll
      for (int mi = 0; mi < 4; ++mi) {
        int row = wm + mi * 16 + l15;
        int slot = (kk * 4 + l4) ^ (row & 7);
        aF[mi] = *(const bf16x8*)&As[row * 64 + slot * 8];
      }
#pragma unroll
      for (int ni = 0; ni < 4; ++ni) {
        int row = wn + ni * 16 + l15;
        int slot = (kk * 4 + l4) ^ (row & 7);
        bF[ni] = *(const bf16x8*)&Bs[row * 64 + slot * 8];
      }
#pragma unroll
      for (int mi = 0; mi < 4; ++mi)
#pragma unroll
        for (int ni = 0; ni < 4; ++ni)
          acc[mi][ni] = __builtin_amdgcn_mfma_f32_16x16x32_bf16(
              bF[ni], aF[mi], acc[mi][ni], 0, 0, 0);
    }
  }

#pragma unroll
  for (int mi = 0; mi < 4; ++mi) {
    int m = bm + wm + mi * 16 + l15;
    float s = 0.f, q = 0.f;
#pragma unroll
    for (int ni = 0; ni < 4; ++ni) {
      int nb = wn + ni * 16 + l4 * 4;
      float4 bv = *(const float4*)(bias + nb);
      ushort4 rv = make_ushort4(0, 0, 0, 0);
      if (m < M) rv = *(const ushort4*)(res + (size_t)m * 256 + nb);
      float y0 = acc[mi][ni][0] + bv.x + b2f(rv.x);
      float y1 = acc[mi][ni][1] + bv.y + b2f(rv.y);
      float y2 = acc[mi][ni][2] + bv.z + b2f(rv.z);
      float y3 = acc[mi][ni][3] + bv.w + b2f(rv.w);
      acc[mi][ni] = (f32x4){y0, y1, y2, y3};
      s += y0 + y1 + y2 + y3;
      q += y0 * y0 + y1 * y1 + y2 * y2 + y3 * y3;
    }
    s += __shfl_xor(s, 16); s += __shfl_xor(s, 32);
    q += __shfl_xor(q, 16); q += __shfl_xor(q, 32);
    if (l4 == 0) part[wid & 3][wm + mi * 16 + l15] = make_float2(s, q);
  }
  __syncthreads();
#pragma unroll
  for (int mi = 0; mi < 4; ++mi) {
    int row = wm + mi * 16 + l15;
    int m = bm + row;
    float S = 0.f, Q = 0.f;
#pragma unroll
    for (int c = 0; c < 4; ++c) {
      float2 pp = part[c][row];
      S += pp.x; Q += pp.y;
    }
    float mean = S * (1.0f / 256.0f);
    float var = fmaxf(Q * (1.0f / 256.0f) - mean * mean, 0.f);
    float rinv = rsqrtf(var + LN_EPS);
    if (m >= M) continue;
#pragma unroll
    for (int ni = 0; ni < 4; ++ni) {
      int nb = wn + ni * 16 + l4 * 4;
      float4 vg = *(const float4*)(gp + nb);
      float4 vb = *(const float4*)(bpar + nb);
      ushort4 o;
      o.x = f2b((acc[mi][ni][0] - mean) * rinv * vg.x + vb.x);
      o.y = f2b((acc[mi][ni][1] - mean) * rinv * vg.y + vb.y);
      o.z = f2b((acc[mi][ni][2] - mean) * rinv * vg.z + vb.z);
      o.w = f2b((acc[mi][ni][3] - mean) * rinv * vg.w + vb.w);
      *(ushort4*)(out + (size_t)m * 256 + nb) = o;
    }
  }
}

// ------------------------------------------------------------------
// per-graph sum (batch sorted), bf16 input (row stride xstride), f32 atomics
// ------------------------------------------------------------------
__global__ void gap_sum_b(const u16* __restrict__ x, int xstride,
                          const int* __restrict__ batch,
                          float* __restrict__ out, int N, int C, int npb) {
  int d = threadIdx.x;            // blockDim.x == C
  int n0 = blockIdx.x * npb;
  if (n0 >= N) return;
  int n1 = min(n0 + npb, N);
  float acc = 0.f;
  int g = batch[n0];
  for (int n = n0; n < n1; ++n) {
    int gn = batch[n];
    if (gn != g) { atomicAdd(&out[g * C + d], acc); acc = 0.f; g = gn; }
    acc += b2f(x[(size_t)n * xstride + d]);
  }
  atomicAdd(&out[g * C + d], acc);
}

// ------------------------------------------------------------------
// H/T tables, parallel over (g, row, d-block): G[g][c] = gapb[g][c]*ginv[g]
// ry<8: H[g][ry][d] = sum_c G[g][c]*Wp[d][ry*128+c]   (H stored bf16)
// ry==8: T[g][d]    = sum_c G[g][c]*Rp[d][c]          (T stays f32)
// ------------------------------------------------------------------
__global__ void hcalc_k(const float* __restrict__ gapb, const float* __restrict__ ginv,
                        const u16* __restrict__ Wp, int ldw,
                        const u16* __restrict__ Rp, int ldr,
                        u16* __restrict__ Hb, float* __restrict__ T, int D) {
  __shared__ float G[128];
  int g = blockIdx.x;
  int t = threadIdx.x;
  G[t] = gapb[g * 128 + t] * ginv[g];
  __syncthreads();
  int ry = blockIdx.y;
  int d = blockIdx.z * 128 + t;
  if (ry < 8) {
    const u16* wp = Wp + (size_t)d * ldw + ry * 128;
    float s = 0.f;
#pragma unroll 4
    for (int c = 0; c < 128; ++c) s += G[c] * b2f(wp[c]);
    Hb[((size_t)g * 8 + ry) * D + d] = f2b(s);
  } else {
    const u16* rp = Rp + (size_t)d * ldr;
    float s = 0.f;
#pragma unroll 4
    for (int c = 0; c < 128; ++c) s += G[c] * b2f(rp[c]);
    T[(size_t)g * D + d] = s;
  }
}

// ------------------------------------------------------------------
// finish: out[n] = leakyrelu(out[n] + (m?m[n]:0) + T[batch[n]]
//                            + sum_{edges e of n} wedge[e]*H[hidx[e]][:])
// ONE NODE PER WAVE: node id wave-uniform -> scalar loads for off/earray;
// only the H-row load stays VMEM. 4-way unrolled.
// ------------------------------------------------------------------
template<int D>
__global__ __launch_bounds__(256)
void finish_k(u16* __restrict__ out, int ldo,
              const u16* __restrict__ m, int ldm,
              const u16* __restrict__ Hb, const float* __restrict__ T,
              const int* __restrict__ off, const int4* __restrict__ earray,
              const int* __restrict__ batch, int N) {
  const int CPL = D / 64;   // cols per lane: 2 (D=128) or 4 (D=256)
  int lane = threadIdx.x & 63;
  int n = __builtin_amdgcn_readfirstlane(blockIdx.x * 4 + (threadIdx.x >> 6));
  if (n >= N) return;
  int cols = lane * CPL;
  float v0, v1, v2 = 0.f, v3 = 0.f;
  if (CPL == 2) {
    unsigned ov = *(const unsigned*)(out + (size_t)n * ldo + cols);
    v0 = b2f((u16)(ov & 0xffff)); v1 = b2f((u16)(ov >> 16));
    if (m) {
      unsigned mv = *(const unsigned*)(m + (size_t)n * ldm + cols);
      v0 += b2f((u16)(mv & 0xffff)); v1 += b2f((u16)(mv >> 16));
    }
    float2 tv = *(const float2*)(T + (size_t)batch[n] * D + cols);
    v0 += tv.x; v1 += tv.y;
  } else {
    ushort4 ov = *(const ushort4*)(out + (size_t)n * ldo + cols);
    v0 = b2f(ov.x); v1 = b2f(ov.y); v2 = b2f(ov.z); v3 = b2f(ov.w);
    if (m) {
      ushort4 mv = *(const ushort4*)(m + (size_t)n * ldm + cols);
      v0 += b2f(mv.x); v1 += b2f(mv.y); v2 += b2f(mv.z); v3 += b2f(mv.w);
    }
    float4 tv = *(const float4*)(T + (size_t)batch[n] * D + cols);
    v0 += tv.x; v1 += tv.y; v2 += tv.z; v3 += tv.w;
  }
  int a = __builtin_amdgcn_readfirstlane(off[n * 8]);
  int b = __builtin_amdgcn_readfirstlane(off[n * 8 + 8]);
  int e = a;
  for (; e + 3 < b; e += 4) {
    int h0i = __builtin_amdgcn_readfirstlane(earray[e].y);
    int w0i = __builtin_amdgcn_readfirstlane(earray[e].z);
    int h1i = __builtin_amdgcn_readfirstlane(earray[e + 1].y);
    int w1i = __builtin_amdgcn_readfirstlane(earray[e + 1].z);
    int h2i = __builtin_amdgcn_readfirstlane(earray[e + 2].y);
    int w2i = __builtin_amdgcn_readfirstlane(earray[e + 2].z);
    int h3i = __builtin_amdgcn_readfirstlane(earray[e + 3].y);
    int w3i = __builtin_amdgcn_readfirstlane(earray[e + 3].z);
    float w0 = __int_as_float(w0i), w1 = __int_as_float(w1i);
    float w2 = __int_as_float(w2i), w3 = __int_as_float(w3i);
    if (CPL == 2) {
      unsigned h0 = *(const unsigned*)(Hb + (size_t)h0i * D + cols);
      unsigned h1 = *(const unsigned*)(Hb + (size_t)h1i * D + cols);
      unsigned h2 = *(const unsigned*)(Hb + (size_t)h2i * D + cols);
      unsigned h3 = *(const unsigned*)(Hb + (size_t)h3i * D + cols);
      v0 += w0 * b2f((u16)(h0 & 0xffff)) + w1 * b2f((u16)(h1 & 0xffff))
          + w2 * b2f((u16)(h2 & 0xffff)) + w3 * b2f((u16)(h3 & 0xffff));
      v1 += w0 * b2f((u16)(h0 >> 16)) + w1 * b2f((u16)(h1 >> 16))
          + w2 * b2f((u16)(h2 >> 16)) + w3 * b2f((u16)(h3 >> 16));
    } else {
      uint2 h0 = *(const uint2*)(Hb + (size_t)h0i * D + cols);
      uint2 h1 = *(const uint2*)(Hb + (size_t)h1i * D + cols);
      uint2 h2 = *(const uint2*)(Hb + (size_t)h2i * D + cols);
      uint2 h3 = *(const uint2*)(Hb + (size_t)h3i * D + cols);
      v0 += w0 * b2f((u16)(h0.x & 0xffff)) + w1 * b2f((u16)(h1.x & 0xffff))
          + w2 * b2f((u16)(h2.x & 0xffff)) + w3 * b2f((u16)(h3.x & 0xffff));
      v1 += w0 * b2f((u16)(h0.x >> 16)) + w1 * b2f((u16)(h1.x >> 16))
          + w2 * b2f((u16)(h2.x >> 16)) + w3 * b2f((u16)(h3.x >> 16));
      v2 += w0 * b2f((u16)(h0.y & 0xffff)) + w1 * b2f((u16)(h1.y & 0xffff))
          + w2 * b2f((u16)(h2.y & 0xffff)) + w3 * b2f((u16)(h3.y & 0xffff));
      v3 += w0 * b2f((u16)(h0.y >> 16)) + w1 * b2f((u16)(h1.y >> 16))
          + w2 * b2f((u16)(h2.y >> 16)) + w3 * b2f((u16)(h3.y >> 16));
    }
  }
  for (; e < b; ++e) {
    int h0i = __builtin_amdgcn_readfirstlane(earray[e].y);
    int w0i = __builtin_amdgcn_readfirstlane(earray[e].z);
    float w0 = __int_as_float(w0i);
    if (CPL == 2) {
      unsigned h0 = *(const unsigned*)(Hb + (size_t)h0i * D + cols);
      v0 += w0 * b2f((u16)(h0 & 0xffff));
      v1 += w0 * b2f((u16)(h0 >> 16));
    } else {
      uint2 h0 = *(const uint2*)(Hb + (size_t)h0i * D + cols);
      v0 += w0 * b2f((u16)(h0.x & 0xffff));
      v1 += w0 * b2f((u16)(h0.x >> 16));
      v2 += w0 * b2f((u16)(h0.y & 0xffff));
      v3 += w0 * b2f((u16)(h0.y >> 16));
    }
  }
  v0 = v0 > 0.f ? v0 : NEG_SLOPE * v0;
  v1 = v1 > 0.f ? v1 : NEG_SLOPE * v1;
  if (CPL == 2) {
    unsigned w = (unsigned)f2b(v0) | ((unsigned)f2b(v1) << 16);
    *(unsigned*)(out + (size_t)n * ldo + cols) = w;
  } else {
    v2 = v2 > 0.f ? v2 : NEG_SLOPE * v2;
    v3 = v3 > 0.f ? v3 : NEG_SLOPE * v3;
    ushort4 w;
    w.x = f2b(v0); w.y = f2b(v1); w.z = f2b(v2); w.w = f2b(v3);
    *(ushort4*)(out + (size_t)n * ldo + cols) = w;
  }
}

// out[g,cls] = (psum[g]*ginv[g]).out_w[cls] + out_b[cls]
__global__ void head_k(const float* __restrict__ psum, const float* __restrict__ ginv,
                       const float* __restrict__ ow, const float* __restrict__ ob,
                       float* __restrict__ out) {
  int gr = blockIdx.x;
  int lane = threadIdx.x;
  float gi = ginv[gr];
  float4 v = *(const float4*)(psum + gr * 256 + lane * 4);
  float p0 = v.x * gi, p1 = v.y * gi, p2 = v.z * gi, p3 = v.w * gi;
  for (int cls = 0; cls < 10; ++cls) {
    float4 w = *(const float4*)(ow + cls * 256 + lane * 4);
    float s = p0 * w.x + p1 * w.y + p2 * w.z + p3 * w.w;
#pragma unroll
    for (int o = 32; o > 0; o >>= 1) s += __shfl_xor(s, o);
    if (lane == 0) out[gr * 10 + cls] = s + ob[cls];
  }
}

// ------------------------------------------------------------------
extern "C" void kernel_launch(void* const* d_in, const int* in_sizes, int n_in,
                              void* d_out, int out_size, void* d_ws, size_t ws_size,
                              hipStream_t stream) {
  const float* x        = (const float*)d_in[0];
  const int*   eidx     = (const int*)d_in[1];
  const int*   eattr    = (const int*)d_in[2];
  const int*   batch    = (const int*)d_in[3];
  const float* Ws       = (const float*)d_in[4];
  const float* Rs       = (const float*)d_in[5];
  const float* Bsb      = (const float*)d_in[6];
  const float* Wf1      = (const float*)d_in[7];
  const float* Rf1      = (const float*)d_in[8];
  const float* Bf1      = (const float*)d_in[9];
  const float* Wf23     = (const float*)d_in[10];
  const float* Rf23     = (const float*)d_in[11];
  const float* Bf23     = (const float*)d_in[12];
  const float* Wf4      = (const float*)d_in[13];
  const float* Rf4      = (const float*)d_in[14];
  const float* Bf4      = (const float*)d_in[15];
  const float* attn_in_w  = (const float*)d_in[16];
  const float* attn_in_b  = (const float*)d_in[17];
  const float* attn_out_w = (const float*)d_in[18];
  const float* attn_out_b = (const float*)d_in[19];
  const float* enc_fc_w   = (const float*)d_in[20];
  const float* enc_fc_b   = (const float*)d_in[21];
  const float* ln_g       = (const float*)d_in[22];
  const float* ln_bb      = (const float*)d_in[23];
  const float* out_w      = (const float*)d_in[24];
  const float* out_b      = (const float*)d_in[25];

  const int N = in_sizes[0] / 128;
  const int E = in_sizes[1] / 2;
  const int NK = N * NREL;
  const int* src = eidx;
  const int* dst = eidx + E;

  // ---- workspace layout (~240 MB; proven safe) ----
  char* p = (char*)d_ws;
  auto alloc = [&](size_t bytes) {
    char* r = p;
    p += (bytes + 255) & ~(size_t)255;
    return r;
  };
  float* ginv  = (float*)alloc(NG * 4);
  float* psum  = (float*)alloc(NG * 256 * 4);
  float* gapb  = (float*)alloc(NG * 128 * 4);
  float* bias14 = (float*)alloc(256 * 4);
  float* bias2m = (float*)alloc(256 * 4);
  float* bias3m = (float*)alloc(256 * 4);
  float* bcomb  = (float*)alloc(256 * 4);
  u16* H5 = (u16*)alloc((size_t)NG * 8 * 128 * 2);
  float* T5 = (float*)alloc((size_t)NG * 128 * 4);
  u16* H6 = (u16*)alloc((size_t)NG * 8 * 128 * 2);
  float* T6 = (float*)alloc((size_t)NG * 128 * 4);
  u16* H7 = (u16*)alloc((size_t)NG * 8 * 256 * 2);
  float* T7 = (float*)alloc((size_t)NG * 256 * 4);
  u16* xb   = (u16*)alloc((size_t)N * 128 * 2);
  u16* xh14 = (u16*)alloc((size_t)N * 256 * 2);   // [x1 | h4], later qpart
  u16* x2m5 = (u16*)alloc((size_t)N * 256 * 2);   // [x2 | m5], later t1
  u16* x3m6 = (u16*)alloc((size_t)N * 256 * 2);   // [x3 | m6]
  u16* h5   = (u16*)alloc((size_t)N * 128 * 2);
  u16* h6   = (u16*)alloc((size_t)N * 128 * 2);
  int* cnt    = (int*)alloc((size_t)NK * 4);
  int* off    = (int*)alloc((size_t)(NK + 1) * 4);
  int* cursor = (int*)alloc((size_t)NK * 4);
  int4* earray = (int4*)alloc((size_t)E * 16);
  int* bsum   = (int*)alloc(2048 * 4);
  // bf16 weight pools [D][ld]
  u16* p14 = (u16*)alloc((size_t)256 * 1152 * 2);
  u16* p2m = (u16*)alloc((size_t)256 * 1152 * 2);
  u16* p3m = (u16*)alloc((size_t)256 * 1152 * 2);
  u16* p5  = (u16*)alloc((size_t)128 * 1280 * 2);
  u16* p6  = (u16*)alloc((size_t)128 * 1280 * 2);
  u16* p7a = (u16*)alloc((size_t)256 * 1152 * 2);
  u16* p7b = (u16*)alloc((size_t)256 * 1152 * 2);
  u16* wc  = (u16*)alloc((size_t)256 * 256 * 2);
  u16* wf  = (u16*)alloc((size_t)256 * 256 * 2);
  u16* S   = (u16*)alloc((size_t)N * 1024 * 2);   // agg scratch [N][8][128]

  u16* qpart = xh14;   // overlays (x1,h4 dead after L5)
  u16* t1 = x2m5;      // dead after L6 chain

  auto cdiv = [](long long a, long long b) { return (int)((a + b - 1) / b); };
  int gm = cdiv(N, 128);
  dim3 g1(gm, 1);

  // ---- CSR build ----
  hipMemsetAsync(cnt, 0, (size_t)NK * 4, stream);
  count_edges_k<<<cdiv(E, 256), 256, 0, stream>>>(dst, eattr, cnt, E);
  int nb = cdiv(NK, SCAN_B * SCAN_I);
  scan1_k<<<nb, SCAN_B, 0, stream>>>(cnt, off, bsum, NK);
  scan2_k<<<1, 1024, 0, stream>>>(bsum, nb);
  scan3_k<<<cdiv(NK, 256), 256, 0, stream>>>(off, bsum, NK, E);
  hipMemcpyAsync(cursor, off, (size_t)NK * 4, hipMemcpyDeviceToDevice, stream);
  scatter_k<<<cdiv(E, 256), 256, 0, stream>>>(src, dst, eattr, batch, cnt, cursor, earray, E);
  graph_inv_k<<<1, 64, 0, stream>>>(batch, ginv, N);

  // ---- weight/bias prep ----
  castf_k<<<cdiv((long long)N * 128, 1024), 256, 0, stream>>>(x, xb, N * 128);
  hipMemsetAsync(p2m, 0, (size_t)256 * 1152 * 2, stream);
  hipMemsetAsync(p3m, 0, (size_t)256 * 1152 * 2, stream);
  dim3 gw(32, 4), gwD2(32, 8), gr(4, 4), grD2(4, 8);
  const float* W6 = Wf23 + (size_t)8 * 256 * 128;
  wtrans_k<<<gw, 256, 0, stream>>>(Ws,  p14,                        128, 0, 128, 1152);
  wtrans_k<<<gr, 256, 0, stream>>>(Rs,  p14 + 1024,                 128, 0, 128, 1152);
  wtrans_k<<<gw, 256, 0, stream>>>(Wf1, p14 + (size_t)128 * 1152,        128, 0, 128, 1152);
  wtrans_k<<<gr, 256, 0, stream>>>(Rf1, p14 + (size_t)128 * 1152 + 1024, 128, 0, 128, 1152);
  wtrans_k<<<gw, 256, 0, stream>>>(Ws + (size_t)8 * 128 * 128, p2m,        128, 0, 128, 1152);
  wtrans_k<<<gr, 256, 0, stream>>>(Rs + 128 * 128,             p2m + 1024, 128, 0, 128, 1152);
  wtrans_k<<<gw, 256, 0, stream>>>(Wf23, p2m + (size_t)128 * 1152, 256, 128, 128, 1152);
  wtrans_k<<<gw, 256, 0, stream>>>(Ws + (size_t)16 * 128 * 128, p3m,        128, 0, 128, 1152);
  wtrans_k<<<gr, 256, 0, stream>>>(Rs + 2 * 128 * 128,          p3m + 1024, 128, 0, 128, 1152);
  wtrans_k<<<gw, 256, 0, stream>>>(W6, p3m + (size_t)128 * 1152, 256, 128, 128, 1152);
  wtrans_k<<<gw, 256, 0, stream>>>(Wf23, p5,        256, 0,   128, 1280);
  wtrans_k<<<gr, 256, 0, stream>>>(Rf23, p5 + 1024, 256, 0,   128, 1280);
  wtrans_k<<<gr, 256, 0, stream>>>(Rf23, p5 + 1152, 256, 128, 128, 1280);
  wtrans_k<<<gw, 256, 0, stream>>>(W6,               p6,        256, 0,   128, 1280);
  wtrans_k<<<gr, 256, 0, stream>>>(Rf23 + 256 * 128, p6 + 1024, 256, 0,   128, 1280);
  wtrans_k<<<gr, 256, 0, stream>>>(Rf23 + 256 * 128, p6 + 1152, 256, 128, 128, 1280);
  wtrans_k<<<gwD2, 256, 0, stream>>>(Wf4, p7a,        256, 0,   256, 1152);
  wtrans_k<<<grD2, 256, 0, stream>>>(Rf4, p7a + 1024, 256, 0,   256, 1152);
  wtrans_k<<<gwD2, 256, 0, stream>>>(Wf4, p7b,        256, 128, 256, 1152);
  wtrans_k<<<grD2, 256, 0, stream>>>(Rf4, p7b + 1024, 256, 128, 256, 1152);
  wcfold_k<<<256, 256, 0, stream>>>(attn_out_w, attn_in_w + (size_t)512 * 256,
                                    attn_in_b + 512, attn_out_b, wc, bcomb);
  castf_k<<<cdiv(256 * 256, 1024), 256, 0, stream>>>(enc_fc_w, wf, 256 * 256);
  hipMemcpyAsync(bias14, Bsb, 512, hipMemcpyDeviceToDevice, stream);
  hipMemcpyAsync(bias14 + 128, Bf1, 512, hipMemcpyDeviceToDevice, stream);
  hipMemsetAsync(bias2m, 0, 1024, stream);
  hipMemcpyAsync(bias2m, Bsb + 128, 512, hipMemcpyDeviceToDevice, stream);
  hipMemsetAsync(bias3m, 0, 1024, stream);
  hipMemcpyAsync(bias3m, Bsb + 256, 512, hipMemcpyDeviceToDevice, stream);

  int aggGrid = cdiv((long long)NK * 16, 256);

  // ---- L1 + L4: [S(x) | x] @ [W1|R1 ; W4|R4] -> [x1 | h4] ----
  agg_csr_b<<<aggGrid, 256, 0, stream>>>(earray, off, xb, 128, S, NK);
  gemm_pool<4, false, 1><<<g1, 512, 0, stream>>>(S, 1024, xb, 128, nullptr, 0,
                                                 p14, 1152, bias14, xh14, N, 256, 1152);
  hipMemsetAsync(gapb, 0, NG * 128 * 4, stream);
  gap_sum_b<<<cdiv(N, 64), 128, 0, stream>>>(xh14, 256, batch, gapb, N, 128, 64);
  hcalc_k<<<dim3(64, 9, 1), 128, 0, stream>>>(gapb, ginv, p2m + (size_t)128 * 1152, 1152,
                                              p5 + 1152, 1280, H5, T5, 128);
  // ---- L2 + m5: [S(x1) | x1] -> [x2 | m5] ----
  agg_csr_b<<<aggGrid, 256, 0, stream>>>(earray, off, xh14, 256, S, NK);
  gemm_pool<4, false, 2><<<g1, 512, 0, stream>>>(S, 1024, xh14, 256, nullptr, 0,
                                                 p2m, 1152, bias2m, x2m5, N, 256, 1152);
  hipMemsetAsync(gapb, 0, NG * 128 * 4, stream);
  gap_sum_b<<<cdiv(N, 64), 128, 0, stream>>>(x2m5, 256, batch, gapb, N, 128, 64);
  hcalc_k<<<dim3(64, 9, 1), 128, 0, stream>>>(gapb, ginv, p3m + (size_t)128 * 1152, 1152,
                                              p6 + 1152, 1280, H6, T6, 128);

  // ---- pass B: L3 + m6 ----
  agg_csr_b<<<aggGrid, 256, 0, stream>>>(earray, off, x2m5, 256, S, NK);
  gemm_pool<4, false, 2><<<g1, 512, 0, stream>>>(S, 1024, x2m5, 256, nullptr, 0,
                                                 p3m, 1152, bias3m, x3m6, N, 256, 1152);
  hipMemsetAsync(gapb, 0, NG * 128 * 4, stream);
  gap_sum_b<<<cdiv(N, 64), 128, 0, stream>>>(x3m6, 256, batch, gapb, N, 128, 64);
  hcalc_k<<<dim3(64, 9, 2), 128, 0, stream>>>(gapb, ginv, p7b, 1152,
                                              p7b + 1024, 1152, H7, T7, 256);

  // ---- L5: [S(h4) | h4 | x1] @ [W5h|R5h|R5s], then finish ----
  agg_csr_b<<<aggGrid, 256, 0, stream>>>(earray, off, xh14 + 128, 256, S, NK);
  gemm_pool<2, false, 0><<<g1, 256, 0, stream>>>(S, 1024, xh14 + 128, 256, xh14, 256,
                                                 p5, 1280, Bf23, h5, N, 128, 1280);
  finish_k<128><<<cdiv(N, 4), 256, 0, stream>>>(h5, 128, x2m5 + 128, 256,
                                                H5, T5, off, earray, batch, N);
  // ---- L6: [S(h5) | h5 | x2] ----
  agg_csr_b<<<aggGrid, 256, 0, stream>>>(earray, off, h5, 128, S, NK);
  gemm_pool<2, false, 0><<<g1, 256, 0, stream>>>(S, 1024, h5, 128, x2m5, 256,
                                                 p6, 1280, Bf23 + 128, h6, N, 128, 1280);
  finish_k<128><<<cdiv(N, 4), 256, 0, stream>>>(h6, 128, x3m6 + 128, 256,
                                                H6, T6, off, earray, batch, N);
  // ---- L7: two K=1152 passes into qpart (D=256), then finish ----
  agg_csr_b<<<aggGrid, 256, 0, stream>>>(earray, off, h6, 128, S, NK);
  gemm_pool<4, false, 0><<<g1, 512, 0, stream>>>(S, 1024, h6, 128, nullptr, 0,
                                                 p7a, 1152, Bf4, qpart, N, 256, 1152);
  agg_csr_b<<<aggGrid, 256, 0, stream>>>(earray, off, x3m6, 256, S, NK);
  gemm_pool<4, true, 0><<<g1, 512, 0, stream>>>(S, 1024, x3m6, 256, nullptr, 0,
                                                p7b, 1152, nullptr, qpart, N, 256, 1152);
  finish_k<256><<<cdiv(N, 4), 256, 0, stream>>>(qpart, 256, nullptr, 0,
                                                H7, T7, off, earray, batch, N);

  // ---- MHA (folded Wc = Wo@Wv) + encoder, LN fused into GEMM epilogue ----
  gemm_ln<<<g1, 512, 0, stream>>>(qpart, wc, bcomb, qpart, ln_g, ln_bb, t1, N);   // a
  gemm_ln<<<g1, 512, 0, stream>>>(t1, wf, enc_fc_b, t1, ln_g, ln_bb, qpart, N);   // o

  // ---- pooled + head ----
  hipMemsetAsync(psum, 0, NG * 256 * 4, stream);
  gap_sum_b<<<cdiv(N, 64), 256, 0, stream>>>(qpart, 256, batch, psum, N, 256, 64);
  head_k<<<64, 64, 0, stream>>>(psum, ginv, out_w, out_b, (float*)d_out);
}

// Round 18
// 1161.714 us; speedup vs baseline: 1.2818x; 1.2818x over previous
//
#include <hip/hip_runtime.h>
#include <cstdint>
#include <cstddef>

#define NREL 8
#define NG 64
#define LN_EPS 1e-5f
#define NEG_SLOPE 0.01f

typedef unsigned short u16;
typedef short bf16x8 __attribute__((ext_vector_type(8)));
typedef float f32x4 __attribute__((ext_vector_type(4)));

static __device__ __forceinline__ float b2f(u16 h) {
  return __uint_as_float(((unsigned)h) << 16);
}
static __device__ __forceinline__ u16 f2b(float f) {
  unsigned u = __float_as_uint(f);
  u += 0x7fffu + ((u >> 16) & 1u);   // RNE
  return (u16)(u >> 16);
}
static __device__ __forceinline__ void upadd8(uint4 v, float* a) {
  a[0] += b2f((u16)(v.x & 0xffff)); a[1] += b2f((u16)(v.x >> 16));
  a[2] += b2f((u16)(v.y & 0xffff)); a[3] += b2f((u16)(v.y >> 16));
  a[4] += b2f((u16)(v.z & 0xffff)); a[5] += b2f((u16)(v.z >> 16));
  a[6] += b2f((u16)(v.w & 0xffff)); a[7] += b2f((u16)(v.w >> 16));
}
static __device__ __forceinline__ uint4 pack8(const float* a) {
  uint4 o;
  o.x = (unsigned)f2b(a[0]) | ((unsigned)f2b(a[1]) << 16);
  o.y = (unsigned)f2b(a[2]) | ((unsigned)f2b(a[3]) << 16);
  o.z = (unsigned)f2b(a[4]) | ((unsigned)f2b(a[5]) << 16);
  o.w = (unsigned)f2b(a[6]) | ((unsigned)f2b(a[7]) << 16);
  return o;
}

// ------------------------------------------------------------------
// setup kernels
// ------------------------------------------------------------------
__global__ void count_edges_k(const int* __restrict__ dst, const int* __restrict__ et,
                              int* __restrict__ cnt, int E) {
  int e = blockIdx.x * blockDim.x + threadIdx.x;
  if (e < E) atomicAdd(&cnt[dst[e] * NREL + et[e]], 1);
}

__global__ void graph_inv_k(const int* __restrict__ batch, float* __restrict__ ginv, int N) {
  int g = threadIdx.x;
  if (g >= NG) return;
  int a, b;
  { int l = 0, h = N; while (l < h) { int m = (l + h) >> 1; if (batch[m] < g) l = m + 1; else h = m; } a = l; }
  { int l = 0, h = N; while (l < h) { int m = (l + h) >> 1; if (batch[m] < g + 1) l = m + 1; else h = m; } b = l; }
  ginv[g] = 1.0f / fmaxf((float)(b - a), 1.0f);
}

#define SCAN_B 256
#define SCAN_I 4

__global__ void scan1_k(const int* __restrict__ in, int* __restrict__ out,
                        int* __restrict__ bsum, int n) {
  __shared__ int sh[SCAN_B];
  int b0 = blockIdx.x * (SCAN_B * SCAN_I);
  int t = threadIdx.x;
  int v[SCAN_I]; int s = 0;
#pragma unroll
  for (int i = 0; i < SCAN_I; ++i) {
    int idx = b0 + t * SCAN_I + i;
    v[i] = idx < n ? in[idx] : 0;
    s += v[i];
  }
  sh[t] = s; __syncthreads();
  for (int off = 1; off < SCAN_B; off <<= 1) {
    int x = (t >= off) ? sh[t - off] : 0; __syncthreads();
    sh[t] += x; __syncthreads();
  }
  int excl = sh[t] - s;
  if (t == SCAN_B - 1) bsum[blockIdx.x] = sh[t];
  int run = excl;
#pragma unroll
  for (int i = 0; i < SCAN_I; ++i) {
    int idx = b0 + t * SCAN_I + i;
    if (idx < n) out[idx] = run;
    run += v[i];
  }
}

__global__ void scan2_k(int* __restrict__ bsum, int nb) {
  __shared__ int sh[1024];
  int t = threadIdx.x;
  int v = t < nb ? bsum[t] : 0;
  sh[t] = v; __syncthreads();
  for (int off = 1; off < 1024; off <<= 1) {
    int x = (t >= off) ? sh[t - off] : 0; __syncthreads();
    sh[t] += x; __syncthreads();
  }
  if (t < nb) bsum[t] = sh[t] - v;
}

__global__ void scan3_k(int* __restrict__ out, const int* __restrict__ bsum, int n, int total) {
  int idx = blockIdx.x * blockDim.x + threadIdx.x;
  if (idx < n) out[idx] += bsum[idx / (SCAN_B * SCAN_I)];
  if (idx == 0) out[n] = total;
}

// scatter edges into CSR order; ONE 16B store per edge:
// earray[p] = {src, batch[src]*8+etype, bits(1/seg_len), 0}
__global__ void scatter_k(const int* __restrict__ src, const int* __restrict__ dst,
                          const int* __restrict__ et, const int* __restrict__ batch,
                          const int* __restrict__ cnt, int* __restrict__ cursor,
                          int4* __restrict__ earray, int E) {
  int e = blockIdx.x * blockDim.x + threadIdx.x;
  if (e >= E) return;
  int s = src[e];
  int r = et[e];
  int key = dst[e] * NREL + r;
  float w = 1.0f / (float)cnt[key];
  int p = atomicAdd(&cursor[key], 1);
  earray[p] = make_int4(s, batch[s] * NREL + r, __float_as_int(w), 0);
}

// ------------------------------------------------------------------
// weight prep: transpose-cast f32 source block -> bf16 pool [D][ldout]
// ------------------------------------------------------------------
__global__ void wtrans_k(const float* __restrict__ in, u16* __restrict__ out,
                         int rstride, int coff, int D, int ldout) {
  __shared__ float tl[32][33];
  int c0 = blockIdx.x * 32;
  int d0 = blockIdx.y * 32;
  int t = threadIdx.x;
  int r = c0 >> 7;
  int rowbase = r * rstride + (c0 & 127) + coff;
#pragma unroll
  for (int i = 0; i < 4; ++i) {
    int cl = (t >> 5) + i * 8;
    tl[cl][t & 31] = in[(size_t)(rowbase + cl) * D + d0 + (t & 31)];
  }
  __syncthreads();
#pragma unroll
  for (int i = 0; i < 4; ++i) {
    int dl = (t >> 5) + i * 8;
    out[(size_t)(d0 + dl) * ldout + c0 + (t & 31)] = f2b(tl[t & 31][dl]);
  }
}

// MHA fold: wc[n][j] = sum_m Wo[n][m]*Wv[m][j] (bf16); bc[n] = Wo[n]·bv + bo[n]
__global__ void wcfold_k(const float* __restrict__ wo, const float* __restrict__ wv,
                         const float* __restrict__ bv, const float* __restrict__ bo,
                         u16* __restrict__ wc, float* __restrict__ bc) {
  __shared__ float worow[256];
  int n = blockIdx.x, j = threadIdx.x;
  worow[j] = wo[n * 256 + j];
  __syncthreads();
  float s = 0.f;
#pragma unroll 4
  for (int m = 0; m < 256; ++m) s += worow[m] * wv[(size_t)m * 256 + j];
  wc[(size_t)n * 256 + j] = f2b(s);
  if (j == 0) {
    float b = bo[n];
    for (int m = 0; m < 256; ++m) b += worow[m] * bv[m];
    bc[n] = b;
  }
}

// plain cast f32 -> bf16 (n multiple of 4)
__global__ void castf_k(const float* __restrict__ in, u16* __restrict__ out, int n) {
  int i = (blockIdx.x * blockDim.x + threadIdx.x) * 4;
  if (i >= n) return;
  float4 v = *(const float4*)(in + i);
  ushort4 o;
  o.x = f2b(v.x); o.y = f2b(v.y); o.z = f2b(v.z); o.w = f2b(v.w);
  *(ushort4*)(out + i) = o;
}

// ------------------------------------------------------------------
// CSR segment aggregation, bf16 in/out, normal stores (L2/LLC-hot for GEMM).
// S[seg][0..128) = (1/max(len,1)) * sum_{e in seg} x[earray[e].x][0..128)
// 16 lanes x 16B per segment; edge loop 4-way unrolled for latency overlap
// ------------------------------------------------------------------
__global__ void agg_csr_b(const int4* __restrict__ earray, const int* __restrict__ off,
                          const u16* __restrict__ xin, int xstride,
                          u16* __restrict__ S, int NSEG) {
  int gid = blockIdx.x * blockDim.x + threadIdx.x;
  int seg = gid >> 4;
  int lane = gid & 15;
  if (seg >= NSEG) return;
  int a = off[seg], b = off[seg + 1];
  float inv = 1.0f / fmaxf((float)(b - a), 1.0f);
  float ac[8] = {0.f, 0.f, 0.f, 0.f, 0.f, 0.f, 0.f, 0.f};
  int e = a;
  for (; e + 3 < b; e += 4) {
    int s0 = earray[e].x, s1 = earray[e + 1].x, s2 = earray[e + 2].x, s3 = earray[e + 3].x;
    uint4 v0 = *(const uint4*)(xin + (size_t)s0 * xstride + lane * 8);
    uint4 v1 = *(const uint4*)(xin + (size_t)s1 * xstride + lane * 8);
    uint4 v2 = *(const uint4*)(xin + (size_t)s2 * xstride + lane * 8);
    uint4 v3 = *(const uint4*)(xin + (size_t)s3 * xstride + lane * 8);
    upadd8(v0, ac); upadd8(v1, ac); upadd8(v2, ac); upadd8(v3, ac);
  }
  for (; e < b; ++e) {
    uint4 v = *(const uint4*)(xin + (size_t)earray[e].x * xstride + lane * 8);
    upadd8(v, ac);
  }
#pragma unroll
  for (int i = 0; i < 8; ++i) ac[i] *= inv;
  *(uint4*)(S + (size_t)seg * 128 + lane * 8) = pack8(ac);
}

// ------------------------------------------------------------------
// pooled bf16 MFMA GEMM: C[m,n] (+)= sum_k A[m,k]*B[n,k]
// A virtual concat: [0,Kagg) from Sa ([M][Kagg]); then 128-col groups from
// dir0/dir1 (row strides ds0/ds1; (k-Kagg)&128 picks dir1). B: [Nout][ldb].
// BM=128, BN=WN*64, BK=64, WN*2 waves.
// ACTMODE: 0 none, 1 all cols, 2 only cols with (n&128)==0
// ------------------------------------------------------------------
template<int WN, bool ACC, int ACTMODE>
__global__ __launch_bounds__(WN * 128)
void gemm_pool(const u16* __restrict__ Sa, int Kagg,
               const u16* __restrict__ dir0, int ds0,
               const u16* __restrict__ dir1, int ds1,
               const u16* __restrict__ Bp, int ldb,
               const float* __restrict__ bias, u16* __restrict__ C,
               int M, int N, int Ktot) {
  constexpr int BN = WN * 64;
  constexpr int CPT = 64 / WN;
  constexpr int SLOTS = CPT / 8;
  __shared__ u16 As[128 * 64];
  __shared__ u16 Bs[BN * 64];
  int bm = blockIdx.x * 128;
  int bn = blockIdx.y * BN;
  int t = threadIdx.x;
  int lane = t & 63;
  int wid = t >> 6;
  int wm = (wid / WN) * 64, wn = (wid % WN) * 64;
  int l15 = lane & 15, l4 = lane >> 4;

  f32x4 acc[4][4];
#pragma unroll
  for (int i = 0; i < 4; ++i)
#pragma unroll
    for (int j = 0; j < 4; ++j)
      acc[i][j] = (f32x4){0.f, 0.f, 0.f, 0.f};

  int srow = t / WN, sub = t % WN;
  int arow = bm + srow;
  int swz = srow & 7;
  int srB = t >> 1;
  int sB32 = (t & 1) * 32;
  int swzB = srB & 7;
  const u16* bpp = Bp + (size_t)(bn + srB) * ldb + sB32;

  for (int k0 = 0; k0 < Ktot; k0 += 64) {
    __syncthreads();
    {
      const u16* ap;
      if (k0 < Kagg) {
        ap = Sa + (size_t)arow * Kagg + k0;
      } else {
        int kd = k0 - Kagg;
        ap = (kd & 128) ? (dir1 + (size_t)arow * ds1 + (kd & 127))
                        : (dir0 + (size_t)arow * ds0 + (kd & 127));
      }
      ap += sub * CPT;
#pragma unroll
      for (int s = 0; s < SLOTS; ++s) {
        uint4 v = make_uint4(0, 0, 0, 0);
        if (arow < M) v = *(const uint4*)(ap + s * 8);
        int slot = (sub * SLOTS + s) ^ swz;
        *(uint4*)&As[srow * 64 + slot * 8] = v;
      }
    }
#pragma unroll
    for (int i = 0; i < 4; ++i) {
      uint4 v = *(const uint4*)(bpp + k0 + i * 8);
      *(uint4*)&Bs[srB * 64 + ((((t & 1) * 4 + i) ^ swzB) << 3)] = v;
    }
    __syncthreads();

#pragma unroll
    for (int kk = 0; kk < 2; ++kk) {
      bf16x8 aF[4], bF[4];
#pragma unroll
      for (int mi = 0; mi < 4; ++mi) {
        int row = wm + mi * 16 + l15;
        int slot = (kk * 4 + l4) ^ (row & 7);
        aF[mi] = *(const bf16x8*)&As[row * 64 + slot * 8];
      }
#pragma unroll
      for (int ni = 0; ni < 4; ++ni) {
        int row = wn + ni * 16 + l15;
        int slot = (kk * 4 + l4) ^ (row & 7);
        bF[ni] = *(const bf16x8*)&Bs[row * 64 + slot * 8];
      }
#pragma unroll
      for (int mi = 0; mi < 4; ++mi)
#pragma unroll
        for (int ni = 0; ni < 4; ++ni)
          acc[mi][ni] = __builtin_amdgcn_mfma_f32_16x16x32_bf16(
              bF[ni], aF[mi], acc[mi][ni], 0, 0, 0);
    }
  }

#pragma unroll
  for (int mi = 0; mi < 4; ++mi) {
    int m = bm + wm + mi * 16 + l15;
    if (m >= M) continue;
#pragma unroll
    for (int ni = 0; ni < 4; ++ni) {
      int nb = bn + wn + ni * 16 + l4 * 4;
      float v0 = acc[mi][ni][0], v1 = acc[mi][ni][1];
      float v2 = acc[mi][ni][2], v3 = acc[mi][ni][3];
      u16* cp = C + (size_t)m * N + nb;
      if (ACC) {
        ushort4 o = *(const ushort4*)cp;
        v0 += b2f(o.x); v1 += b2f(o.y); v2 += b2f(o.z); v3 += b2f(o.w);
      } else {
        float4 bv = *(const float4*)(bias + nb);
        v0 += bv.x; v1 += bv.y; v2 += bv.z; v3 += bv.w;
      }
      bool da = (ACTMODE == 1) || (ACTMODE == 2 && !(nb & 128));
      if (da) {
        v0 = v0 > 0.f ? v0 : NEG_SLOPE * v0;
        v1 = v1 > 0.f ? v1 : NEG_SLOPE * v1;
        v2 = v2 > 0.f ? v2 : NEG_SLOPE * v2;
        v3 = v3 > 0.f ? v3 : NEG_SLOPE * v3;
      }
      ushort4 o;
      o.x = f2b(v0); o.y = f2b(v1); o.z = f2b(v2); o.w = f2b(v3);
      *(ushort4*)cp = o;
    }
  }
}

// ------------------------------------------------------------------
// GEMM + residual + LayerNorm fused (encoder): out = LN(A@B^T + bias + res)
// A [M][256], B [256][256], BM=128, BN=256 (full row in block), 512 thr.
// ------------------------------------------------------------------
__global__ __launch_bounds__(512)
void gemm_ln(const u16* __restrict__ A, const u16* __restrict__ Bp,
             const float* __restrict__ bias, const u16* __restrict__ res,
             const float* __restrict__ gp, const float* __restrict__ bpar,
             u16* __restrict__ out, int M) {
  __shared__ u16 As[128 * 64];
  __shared__ u16 Bs[256 * 64];
  __shared__ float2 part[4][128];
  int bm = blockIdx.x * 128;
  int t = threadIdx.x;
  int lane = t & 63;
  int wid = t >> 6;
  int wm = (wid >> 2) * 64, wn = (wid & 3) * 64;
  int l15 = lane & 15, l4 = lane >> 4;

  f32x4 acc[4][4];
#pragma unroll
  for (int i = 0; i < 4; ++i)
#pragma unroll
    for (int j = 0; j < 4; ++j)
      acc[i][j] = (f32x4){0.f, 0.f, 0.f, 0.f};

  int srow = t >> 2, sub = t & 3;
  int arow = bm + srow;
  int swz = srow & 7;
  int srB = t >> 1;
  int sB32 = (t & 1) * 32;
  int swzB = srB & 7;
  const u16* bpp = Bp + (size_t)srB * 256 + sB32;

  for (int k0 = 0; k0 < 256; k0 += 64) {
    __syncthreads();
    {
      const u16* ap = A + (size_t)arow * 256 + k0 + sub * 16;
#pragma unroll
      for (int s = 0; s < 2; ++s) {
        uint4 v = make_uint4(0, 0, 0, 0);
        if (arow < M) v = *(const uint4*)(ap + s * 8);
        int slot = (sub * 2 + s) ^ swz;
        *(uint4*)&As[srow * 64 + slot * 8] = v;
      }
    }
#pragma unroll
    for (int i = 0; i < 4; ++i) {
      uint4 v = *(const uint4*)(bpp + k0 + i * 8);
      *(uint4*)&Bs[srB * 64 + ((((t & 1) * 4 + i) ^ swzB) << 3)] = v;
    }
    __syncthreads();

#pragma unroll
    for (int kk = 0; kk < 2; ++kk) {
      bf16x8 aF[4], bF[4];
#pragma unroll
      for (int mi = 0; mi < 4; ++mi) {
        int row = wm + mi * 16 + l15;
        int slot = (kk * 4 + l4) ^ (row & 7);
        aF[mi] = *(const bf16x8*)&As[row * 64 + slot * 8];
      }
#pragma unroll
      for (int ni = 0; ni < 4; ++ni) {
        int row = wn + ni * 16 + l15;
        int slot = (kk * 4 + l4) ^ (row & 7);
        bF[ni] = *(const bf16x8*)&Bs[row * 64 + slot * 8];
      }
#pragma unroll
      for (int mi = 0; mi < 4; ++mi)
#pragma unroll
        for (int ni = 0; ni < 4; ++ni)
          acc[mi][ni] = __builtin_amdgcn_mfma_f32_16x16x32_bf16(
              bF[ni], aF[mi], acc[mi][ni], 0, 0, 0);
    }
  }

#pragma unroll
  for (int mi = 0; mi < 4; ++mi) {
    int m = bm + wm + mi * 16 + l15;
    float s = 0.f, q = 0.f;
#pragma unroll
    for (int ni = 0; ni < 4; ++ni) {
      int nb = wn + ni * 16 + l4 * 4;
      float4 bv = *(const float4*)(bias + nb);
      ushort4 rv = make_ushort4(0, 0, 0, 0);
      if (m < M) rv = *(const ushort4*)(res + (size_t)m * 256 + nb);
      float y0 = acc[mi][ni][0] + bv.x + b2f(rv.x);
      float y1 = acc[mi][ni][1] + bv.y + b2f(rv.y);
      float y2 = acc[mi][ni][2] + bv.z + b2f(rv.z);
      float y3 = acc[mi][ni][3] + bv.w + b2f(rv.w);
      acc[mi][ni] = (f32x4){y0, y1, y2, y3};
      s += y0 + y1 + y2 + y3;
      q += y0 * y0 + y1 * y1 + y2 * y2 + y3 * y3;
    }
    s += __shfl_xor(s, 16); s += __shfl_xor(s, 32);
    q += __shfl_xor(q, 16); q += __shfl_xor(q, 32);
    if (l4 == 0) part[wid & 3][wm + mi * 16 + l15] = make_float2(s, q);
  }
  __syncthreads();
#pragma unroll
  for (int mi = 0; mi < 4; ++mi) {
    int row = wm + mi * 16 + l15;
    int m = bm + row;
    float S = 0.f, Q = 0.f;
#pragma unroll
    for (int c = 0; c < 4; ++c) {
      float2 pp = part[c][row];
      S += pp.x; Q += pp.y;
    }
    float mean = S * (1.0f / 256.0f);
    float var = fmaxf(Q * (1.0f / 256.0f) - mean * mean, 0.f);
    float rinv = rsqrtf(var + LN_EPS);
    if (m >= M) continue;
#pragma unroll
    for (int ni = 0; ni < 4; ++ni) {
      int nb = wn + ni * 16 + l4 * 4;
      float4 vg = *(const float4*)(gp + nb);
      float4 vb = *(const float4*)(bpar + nb);
      ushort4 o;
      o.x = f2b((acc[mi][ni][0] - mean) * rinv * vg.x + vb.x);
      o.y = f2b((acc[mi][ni][1] - mean) * rinv * vg.y + vb.y);
      o.z = f2b((acc[mi][ni][2] - mean) * rinv * vg.z + vb.z);
      o.w = f2b((acc[mi][ni][3] - mean) * rinv * vg.w + vb.w);
      *(ushort4*)(out + (size_t)m * 256 + nb) = o;
    }
  }
}

// ------------------------------------------------------------------
// per-graph sum (batch sorted), bf16 input (row stride xstride), f32 atomics
// ------------------------------------------------------------------
__global__ void gap_sum_b(const u16* __restrict__ x, int xstride,
                          const int* __restrict__ batch,
                          float* __restrict__ out, int N, int C, int npb) {
  int d = threadIdx.x;            // blockDim.x == C
  int n0 = blockIdx.x * npb;
  if (n0 >= N) return;
  int n1 = min(n0 + npb, N);
  float acc = 0.f;
  int g = batch[n0];
  for (int n = n0; n < n1; ++n) {
    int gn = batch[n];
    if (gn != g) { atomicAdd(&out[g * C + d], acc); acc = 0.f; g = gn; }
    acc += b2f(x[(size_t)n * xstride + d]);
  }
  atomicAdd(&out[g * C + d], acc);
}

// ------------------------------------------------------------------
// H/T tables, parallel over (g, row, d-block): G[g][c] = gapb[g][c]*ginv[g]
// ry<8: H[g][ry][d] = sum_c G[g][c]*Wp[d][ry*128+c]   (H stored bf16)
// ry==8: T[g][d]    = sum_c G[g][c]*Rp[d][c]          (T stays f32)
// ------------------------------------------------------------------
__global__ void hcalc_k(const float* __restrict__ gapb, const float* __restrict__ ginv,
                        const u16* __restrict__ Wp, int ldw,
                        const u16* __restrict__ Rp, int ldr,
                        u16* __restrict__ Hb, float* __restrict__ T, int D) {
  __shared__ float G[128];
  int g = blockIdx.x;
  int t = threadIdx.x;
  G[t] = gapb[g * 128 + t] * ginv[g];
  __syncthreads();
  int ry = blockIdx.y;
  int d = blockIdx.z * 128 + t;
  if (ry < 8) {
    const u16* wp = Wp + (size_t)d * ldw + ry * 128;
    float s = 0.f;
#pragma unroll 4
    for (int c = 0; c < 128; ++c) s += G[c] * b2f(wp[c]);
    Hb[((size_t)g * 8 + ry) * D + d] = f2b(s);
  } else {
    const u16* rp = Rp + (size_t)d * ldr;
    float s = 0.f;
#pragma unroll 4
    for (int c = 0; c < 128; ++c) s += G[c] * b2f(rp[c]);
    T[(size_t)g * D + d] = s;
  }
}

// ------------------------------------------------------------------
// finish: out[n] = leakyrelu(out[n] + (m?m[n]:0) + T[batch[n]]
//                            + sum_{edges e of n} wedge[e]*H[hidx[e]][:])
// ONE NODE PER WAVE: node id wave-uniform -> scalar loads for off/earray;
// only the H-row load stays VMEM. 4-way unrolled.
// ------------------------------------------------------------------
template<int D>
__global__ __launch_bounds__(256)
void finish_k(u16* __restrict__ out, int ldo,
              const u16* __restrict__ m, int ldm,
              const u16* __restrict__ Hb, const float* __restrict__ T,
              const int* __restrict__ off, const int4* __restrict__ earray,
              const int* __restrict__ batch, int N) {
  const int CPL = D / 64;   // cols per lane: 2 (D=128) or 4 (D=256)
  int lane = threadIdx.x & 63;
  int n = __builtin_amdgcn_readfirstlane(blockIdx.x * 4 + (threadIdx.x >> 6));
  if (n >= N) return;
  int cols = lane * CPL;
  float v0, v1, v2 = 0.f, v3 = 0.f;
  if (CPL == 2) {
    unsigned ov = *(const unsigned*)(out + (size_t)n * ldo + cols);
    v0 = b2f((u16)(ov & 0xffff)); v1 = b2f((u16)(ov >> 16));
    if (m) {
      unsigned mv = *(const unsigned*)(m + (size_t)n * ldm + cols);
      v0 += b2f((u16)(mv & 0xffff)); v1 += b2f((u16)(mv >> 16));
    }
    float2 tv = *(const float2*)(T + (size_t)batch[n] * D + cols);
    v0 += tv.x; v1 += tv.y;
  } else {
    ushort4 ov = *(const ushort4*)(out + (size_t)n * ldo + cols);
    v0 = b2f(ov.x); v1 = b2f(ov.y); v2 = b2f(ov.z); v3 = b2f(ov.w);
    if (m) {
      ushort4 mv = *(const ushort4*)(m + (size_t)n * ldm + cols);
      v0 += b2f(mv.x); v1 += b2f(mv.y); v2 += b2f(mv.z); v3 += b2f(mv.w);
    }
    float4 tv = *(const float4*)(T + (size_t)batch[n] * D + cols);
    v0 += tv.x; v1 += tv.y; v2 += tv.z; v3 += tv.w;
  }
  int a = __builtin_amdgcn_readfirstlane(off[n * 8]);
  int b = __builtin_amdgcn_readfirstlane(off[n * 8 + 8]);
  int e = a;
  for (; e + 3 < b; e += 4) {
    int h0i = __builtin_amdgcn_readfirstlane(earray[e].y);
    int w0i = __builtin_amdgcn_readfirstlane(earray[e].z);
    int h1i = __builtin_amdgcn_readfirstlane(earray[e + 1].y);
    int w1i = __builtin_amdgcn_readfirstlane(earray[e + 1].z);
    int h2i = __builtin_amdgcn_readfirstlane(earray[e + 2].y);
    int w2i = __builtin_amdgcn_readfirstlane(earray[e + 2].z);
    int h3i = __builtin_amdgcn_readfirstlane(earray[e + 3].y);
    int w3i = __builtin_amdgcn_readfirstlane(earray[e + 3].z);
    float w0 = __int_as_float(w0i), w1 = __int_as_float(w1i);
    float w2 = __int_as_float(w2i), w3 = __int_as_float(w3i);
    if (CPL == 2) {
      unsigned h0 = *(const unsigned*)(Hb + (size_t)h0i * D + cols);
      unsigned h1 = *(const unsigned*)(Hb + (size_t)h1i * D + cols);
      unsigned h2 = *(const unsigned*)(Hb + (size_t)h2i * D + cols);
      unsigned h3 = *(const unsigned*)(Hb + (size_t)h3i * D + cols);
      v0 += w0 * b2f((u16)(h0 & 0xffff)) + w1 * b2f((u16)(h1 & 0xffff))
          + w2 * b2f((u16)(h2 & 0xffff)) + w3 * b2f((u16)(h3 & 0xffff));
      v1 += w0 * b2f((u16)(h0 >> 16)) + w1 * b2f((u16)(h1 >> 16))
          + w2 * b2f((u16)(h2 >> 16)) + w3 * b2f((u16)(h3 >> 16));
    } else {
      uint2 h0 = *(const uint2*)(Hb + (size_t)h0i * D + cols);
      uint2 h1 = *(const uint2*)(Hb + (size_t)h1i * D + cols);
      uint2 h2 = *(const uint2*)(Hb + (size_t)h2i * D + cols);
      uint2 h3 = *(const uint2*)(Hb + (size_t)h3i * D + cols);
      v0 += w0 * b2f((u16)(h0.x & 0xffff)) + w1 * b2f((u16)(h1.x & 0xffff))
          + w2 * b2f((u16)(h2.x & 0xffff)) + w3 * b2f((u16)(h3.x & 0xffff));
      v1 += w0 * b2f((u16)(h0.x >> 16)) + w1 * b2f((u16)(h1.x >> 16))
          + w2 * b2f((u16)(h2.x >> 16)) + w3 * b2f((u16)(h3.x >> 16));
      v2 += w0 * b2f((u16)(h0.y & 0xffff)) + w1 * b2f((u16)(h1.y & 0xffff))
          + w2 * b2f((u16)(h2.y & 0xffff)) + w3 * b2f((u16)(h3.y & 0xffff));
      v3 += w0 * b2f((u16)(h0.y >> 16)) + w1 * b2f((u16)(h1.y >> 16))
          + w2 * b2f((u16)(h2.y >> 16)) + w3 * b2f((u16)(h3.y >> 16));
    }
  }
  for (; e < b; ++e) {
    int h0i = __builtin_amdgcn_readfirstlane(earray[e].y);
    int w0i = __builtin_amdgcn_readfirstlane(earray[e].z);
    float w0 = __int_as_float(w0i);
    if (CPL == 2) {
      unsigned h0 = *(const unsigned*)(Hb + (size_t)h0i * D + cols);
      v0 += w0 * b2f((u16)(h0 & 0xffff));
      v1 += w0 * b2f((u16)(h0 >> 16));
    } else {
      uint2 h0 = *(const uint2*)(Hb + (size_t)h0i * D + cols);
      v0 += w0 * b2f((u16)(h0.x & 0xffff));
      v1 += w0 * b2f((u16)(h0.x >> 16));
      v2 += w0 * b2f((u16)(h0.y & 0xffff));
      v3 += w0 * b2f((u16)(h0.y >> 16));
    }
  }
  v0 = v0 > 0.f ? v0 : NEG_SLOPE * v0;
  v1 = v1 > 0.f ? v1 : NEG_SLOPE * v1;
  if (CPL == 2) {
    unsigned w = (unsigned)f2b(v0) | ((unsigned)f2b(v1) << 16);
    *(unsigned*)(out + (size_t)n * ldo + cols) = w;
  } else {
    v2 = v2 > 0.f ? v2 : NEG_SLOPE * v2;
    v3 = v3 > 0.f ? v3 : NEG_SLOPE * v3;
    ushort4 w;
    w.x = f2b(v0); w.y = f2b(v1); w.z = f2b(v2); w.w = f2b(v3);
    *(ushort4*)(out + (size_t)n * ldo + cols) = w;
  }
}

// out[g,cls] = (psum[g]*ginv[g]).out_w[cls] + out_b[cls]
__global__ void head_k(const float* __restrict__ psum, const float* __restrict__ ginv,
                       const float* __restrict__ ow, const float* __restrict__ ob,
                       float* __restrict__ out) {
  int gr = blockIdx.x;
  int lane = threadIdx.x;
  float gi = ginv[gr];
  float4 v = *(const float4*)(psum + gr * 256 + lane * 4);
  float p0 = v.x * gi, p1 = v.y * gi, p2 = v.z * gi, p3 = v.w * gi;
  for (int cls = 0; cls < 10; ++cls) {
    float4 w = *(const float4*)(ow + cls * 256 + lane * 4);
    float s = p0 * w.x + p1 * w.y + p2 * w.z + p3 * w.w;
#pragma unroll
    for (int o = 32; o > 0; o >>= 1) s += __shfl_xor(s, o);
    if (lane == 0) out[gr * 10 + cls] = s + ob[cls];
  }
}

// ------------------------------------------------------------------
extern "C" void kernel_launch(void* const* d_in, const int* in_sizes, int n_in,
                              void* d_out, int out_size, void* d_ws, size_t ws_size,
                              hipStream_t stream) {
  const float* x        = (const float*)d_in[0];
  const int*   eidx     = (const int*)d_in[1];
  const int*   eattr    = (const int*)d_in[2];
  const int*   batch    = (const int*)d_in[3];
  const float* Ws       = (const float*)d_in[4];
  const float* Rs       = (const float*)d_in[5];
  const float* Bsb      = (const float*)d_in[6];
  const float* Wf1      = (const float*)d_in[7];
  const float* Rf1      = (const float*)d_in[8];
  const float* Bf1      = (const float*)d_in[9];
  const float* Wf23     = (const float*)d_in[10];
  const float* Rf23     = (const float*)d_in[11];
  const float* Bf23     = (const float*)d_in[12];
  const float* Wf4      = (const float*)d_in[13];
  const float* Rf4      = (const float*)d_in[14];
  const float* Bf4      = (const float*)d_in[15];
  const float* attn_in_w  = (const float*)d_in[16];
  const float* attn_in_b  = (const float*)d_in[17];
  const float* attn_out_w = (const float*)d_in[18];
  const float* attn_out_b = (const float*)d_in[19];
  const float* enc_fc_w   = (const float*)d_in[20];
  const float* enc_fc_b   = (const float*)d_in[21];
  const float* ln_g       = (const float*)d_in[22];
  const float* ln_bb      = (const float*)d_in[23];
  const float* out_w      = (const float*)d_in[24];
  const float* out_b      = (const float*)d_in[25];

  const int N = in_sizes[0] / 128;
  const int E = in_sizes[1] / 2;
  const int NK = N * NREL;
  const int* src = eidx;
  const int* dst = eidx + E;

  // ---- workspace layout (~240 MB; proven safe) ----
  char* p = (char*)d_ws;
  auto alloc = [&](size_t bytes) {
    char* r = p;
    p += (bytes + 255) & ~(size_t)255;
    return r;
  };
  float* ginv  = (float*)alloc(NG * 4);
  float* psum  = (float*)alloc(NG * 256 * 4);
  float* gapb  = (float*)alloc(NG * 128 * 4);
  float* bias14 = (float*)alloc(256 * 4);
  float* bias2m = (float*)alloc(256 * 4);
  float* bias3m = (float*)alloc(256 * 4);
  float* bcomb  = (float*)alloc(256 * 4);
  u16* H5 = (u16*)alloc((size_t)NG * 8 * 128 * 2);
  float* T5 = (float*)alloc((size_t)NG * 128 * 4);
  u16* H6 = (u16*)alloc((size_t)NG * 8 * 128 * 2);
  float* T6 = (float*)alloc((size_t)NG * 128 * 4);
  u16* H7 = (u16*)alloc((size_t)NG * 8 * 256 * 2);
  float* T7 = (float*)alloc((size_t)NG * 256 * 4);
  u16* xb   = (u16*)alloc((size_t)N * 128 * 2);
  u16* xh14 = (u16*)alloc((size_t)N * 256 * 2);   // [x1 | h4], later qpart
  u16* x2m5 = (u16*)alloc((size_t)N * 256 * 2);   // [x2 | m5], later t1
  u16* x3m6 = (u16*)alloc((size_t)N * 256 * 2);   // [x3 | m6]
  u16* h5   = (u16*)alloc((size_t)N * 128 * 2);
  u16* h6   = (u16*)alloc((size_t)N * 128 * 2);
  int* cnt    = (int*)alloc((size_t)NK * 4);
  int* off    = (int*)alloc((size_t)(NK + 1) * 4);
  int* cursor = (int*)alloc((size_t)NK * 4);
  int4* earray = (int4*)alloc((size_t)E * 16);
  int* bsum   = (int*)alloc(2048 * 4);
  // bf16 weight pools [D][ld]
  u16* p14 = (u16*)alloc((size_t)256 * 1152 * 2);
  u16* p2m = (u16*)alloc((size_t)256 * 1152 * 2);
  u16* p3m = (u16*)alloc((size_t)256 * 1152 * 2);
  u16* p5  = (u16*)alloc((size_t)128 * 1280 * 2);
  u16* p6  = (u16*)alloc((size_t)128 * 1280 * 2);
  u16* p7a = (u16*)alloc((size_t)256 * 1152 * 2);
  u16* p7b = (u16*)alloc((size_t)256 * 1152 * 2);
  u16* wc  = (u16*)alloc((size_t)256 * 256 * 2);
  u16* wf  = (u16*)alloc((size_t)256 * 256 * 2);
  u16* S   = (u16*)alloc((size_t)N * 1024 * 2);   // agg scratch [N][8][128]

  u16* qpart = xh14;   // overlays (x1,h4 dead after L5)
  u16* t1 = x2m5;      // dead after L6 chain

  auto cdiv = [](long long a, long long b) { return (int)((a + b - 1) / b); };
  int gm = cdiv(N, 128);
  dim3 g1(gm, 1);

  // ---- CSR build ----
  hipMemsetAsync(cnt, 0, (size_t)NK * 4, stream);
  count_edges_k<<<cdiv(E, 256), 256, 0, stream>>>(dst, eattr, cnt, E);
  int nb = cdiv(NK, SCAN_B * SCAN_I);
  scan1_k<<<nb, SCAN_B, 0, stream>>>(cnt, off, bsum, NK);
  scan2_k<<<1, 1024, 0, stream>>>(bsum, nb);
  scan3_k<<<cdiv(NK, 256), 256, 0, stream>>>(off, bsum, NK, E);
  hipMemcpyAsync(cursor, off, (size_t)NK * 4, hipMemcpyDeviceToDevice, stream);
  scatter_k<<<cdiv(E, 256), 256, 0, stream>>>(src, dst, eattr, batch, cnt, cursor, earray, E);
  graph_inv_k<<<1, 64, 0, stream>>>(batch, ginv, N);

  // ---- weight/bias prep ----
  castf_k<<<cdiv((long long)N * 128, 1024), 256, 0, stream>>>(x, xb, N * 128);
  hipMemsetAsync(p2m, 0, (size_t)256 * 1152 * 2, stream);
  hipMemsetAsync(p3m, 0, (size_t)256 * 1152 * 2, stream);
  dim3 gw(32, 4), gwD2(32, 8), gr(4, 4), grD2(4, 8);
  const float* W6 = Wf23 + (size_t)8 * 256 * 128;
  wtrans_k<<<gw, 256, 0, stream>>>(Ws,  p14,                        128, 0, 128, 1152);
  wtrans_k<<<gr, 256, 0, stream>>>(Rs,  p14 + 1024,                 128, 0, 128, 1152);
  wtrans_k<<<gw, 256, 0, stream>>>(Wf1, p14 + (size_t)128 * 1152,        128, 0, 128, 1152);
  wtrans_k<<<gr, 256, 0, stream>>>(Rf1, p14 + (size_t)128 * 1152 + 1024, 128, 0, 128, 1152);
  wtrans_k<<<gw, 256, 0, stream>>>(Ws + (size_t)8 * 128 * 128, p2m,        128, 0, 128, 1152);
  wtrans_k<<<gr, 256, 0, stream>>>(Rs + 128 * 128,             p2m + 1024, 128, 0, 128, 1152);
  wtrans_k<<<gw, 256, 0, stream>>>(Wf23, p2m + (size_t)128 * 1152, 256, 128, 128, 1152);
  wtrans_k<<<gw, 256, 0, stream>>>(Ws + (size_t)16 * 128 * 128, p3m,        128, 0, 128, 1152);
  wtrans_k<<<gr, 256, 0, stream>>>(Rs + 2 * 128 * 128,          p3m + 1024, 128, 0, 128, 1152);
  wtrans_k<<<gw, 256, 0, stream>>>(W6, p3m + (size_t)128 * 1152, 256, 128, 128, 1152);
  wtrans_k<<<gw, 256, 0, stream>>>(Wf23, p5,        256, 0,   128, 1280);
  wtrans_k<<<gr, 256, 0, stream>>>(Rf23, p5 + 1024, 256, 0,   128, 1280);
  wtrans_k<<<gr, 256, 0, stream>>>(Rf23, p5 + 1152, 256, 128, 128, 1280);
  wtrans_k<<<gw, 256, 0, stream>>>(W6,               p6,        256, 0,   128, 1280);
  wtrans_k<<<gr, 256, 0, stream>>>(Rf23 + 256 * 128, p6 + 1024, 256, 0,   128, 1280);
  wtrans_k<<<gr, 256, 0, stream>>>(Rf23 + 256 * 128, p6 + 1152, 256, 128, 128, 1280);
  wtrans_k<<<gwD2, 256, 0, stream>>>(Wf4, p7a,        256, 0,   256, 1152);
  wtrans_k<<<grD2, 256, 0, stream>>>(Rf4, p7a + 1024, 256, 0,   256, 1152);
  wtrans_k<<<gwD2, 256, 0, stream>>>(Wf4, p7b,        256, 128, 256, 1152);
  wtrans_k<<<grD2, 256, 0, stream>>>(Rf4, p7b + 1024, 256, 128, 256, 1152);
  wcfold_k<<<256, 256, 0, stream>>>(attn_out_w, attn_in_w + (size_t)512 * 256,
                                    attn_in_b + 512, attn_out_b, wc, bcomb);
  castf_k<<<cdiv(256 * 256, 1024), 256, 0, stream>>>(enc_fc_w, wf, 256 * 256);
  hipMemcpyAsync(bias14, Bsb, 512, hipMemcpyDeviceToDevice, stream);
  hipMemcpyAsync(bias14 + 128, Bf1, 512, hipMemcpyDeviceToDevice, stream);
  hipMemsetAsync(bias2m, 0, 1024, stream);
  hipMemcpyAsync(bias2m, Bsb + 128, 512, hipMemcpyDeviceToDevice, stream);
  hipMemsetAsync(bias3m, 0, 1024, stream);
  hipMemcpyAsync(bias3m, Bsb + 256, 512, hipMemcpyDeviceToDevice, stream);

  int aggGrid = cdiv((long long)NK * 16, 256);

  // ---- L1 + L4: [S(x) | x] @ [W1|R1 ; W4|R4] -> [x1 | h4] ----
  agg_csr_b<<<aggGrid, 256, 0, stream>>>(earray, off, xb, 128, S, NK);
  gemm_pool<4, false, 1><<<g1, 512, 0, stream>>>(S, 1024, xb, 128, nullptr, 0,
                                                 p14, 1152, bias14, xh14, N, 256, 1152);
  hipMemsetAsync(gapb, 0, NG * 128 * 4, stream);
  gap_sum_b<<<cdiv(N, 64), 128, 0, stream>>>(xh14, 256, batch, gapb, N, 128, 64);
  hcalc_k<<<dim3(64, 9, 1), 128, 0, stream>>>(gapb, ginv, p2m + (size_t)128 * 1152, 1152,
                                              p5 + 1152, 1280, H5, T5, 128);
  // ---- L2 + m5: [S(x1) | x1] -> [x2 | m5] ----
  agg_csr_b<<<aggGrid, 256, 0, stream>>>(earray, off, xh14, 256, S, NK);
  gemm_pool<4, false, 2><<<g1, 512, 0, stream>>>(S, 1024, xh14, 256, nullptr, 0,
                                                 p2m, 1152, bias2m, x2m5, N, 256, 1152);
  hipMemsetAsync(gapb, 0, NG * 128 * 4, stream);
  gap_sum_b<<<cdiv(N, 64), 128, 0, stream>>>(x2m5, 256, batch, gapb, N, 128, 64);
  hcalc_k<<<dim3(64, 9, 1), 128, 0, stream>>>(gapb, ginv, p3m + (size_t)128 * 1152, 1152,
                                              p6 + 1152, 1280, H6, T6, 128);

  // ---- pass B: L3 + m6 ----
  agg_csr_b<<<aggGrid, 256, 0, stream>>>(earray, off, x2m5, 256, S, NK);
  gemm_pool<4, false, 2><<<g1, 512, 0, stream>>>(S, 1024, x2m5, 256, nullptr, 0,
                                                 p3m, 1152, bias3m, x3m6, N, 256, 1152);
  hipMemsetAsync(gapb, 0, NG * 128 * 4, stream);
  gap_sum_b<<<cdiv(N, 64), 128, 0, stream>>>(x3m6, 256, batch, gapb, N, 128, 64);
  hcalc_k<<<dim3(64, 9, 2), 128, 0, stream>>>(gapb, ginv, p7b, 1152,
                                              p7b + 1024, 1152, H7, T7, 256);

  // ---- L5: [S(h4) | h4 | x1] @ [W5h|R5h|R5s], then finish ----
  agg_csr_b<<<aggGrid, 256, 0, stream>>>(earray, off, xh14 + 128, 256, S, NK);
  gemm_pool<2, false, 0><<<g1, 256, 0, stream>>>(S, 1024, xh14 + 128, 256, xh14, 256,
                                                 p5, 1280, Bf23, h5, N, 128, 1280);
  finish_k<128><<<cdiv(N, 4), 256, 0, stream>>>(h5, 128, x2m5 + 128, 256,
                                                H5, T5, off, earray, batch, N);
  // ---- L6: [S(h5) | h5 | x2] ----
  agg_csr_b<<<aggGrid, 256, 0, stream>>>(earray, off, h5, 128, S, NK);
  gemm_pool<2, false, 0><<<g1, 256, 0, stream>>>(S, 1024, h5, 128, x2m5, 256,
                                                 p6, 1280, Bf23 + 128, h6, N, 128, 1280);
  finish_k<128><<<cdiv(N, 4), 256, 0, stream>>>(h6, 128, x3m6 + 128, 256,
                                                H6, T6, off, earray, batch, N);
  // ---- L7: two K=1152 passes into qpart (D=256), then finish ----
  agg_csr_b<<<aggGrid, 256, 0, stream>>>(earray, off, h6, 128, S, NK);
  gemm_pool<4, false, 0><<<g1, 512, 0, stream>>>(S, 1024, h6, 128, nullptr, 0,
                                                 p7a, 1152, Bf4, qpart, N, 256, 1152);
  agg_csr_b<<<aggGrid, 256, 0, stream>>>(earray, off, x3m6, 256, S, NK);
  gemm_pool<4, true, 0><<<g1, 512, 0, stream>>>(S, 1024, x3m6, 256, nullptr, 0,
                                                p7b, 1152, nullptr, qpart, N, 256, 1152);
  finish_k<256><<<cdiv(N, 4), 256, 0, stream>>>(qpart, 256, nullptr, 0,
                                                H7, T7, off, earray, batch, N);

  // ---- MHA (folded Wc = Wo@Wv) + encoder, LN fused into GEMM epilogue ----
  gemm_ln<<<g1, 512, 0, stream>>>(qpart, wc, bcomb, qpart, ln_g, ln_bb, t1, N);   // a
  gemm_ln<<<g1, 512, 0, stream>>>(t1, wf, enc_fc_b, t1, ln_g, ln_bb, qpart, N);   // o

  // ---- pooled + head ----
  hipMemsetAsync(psum, 0, NG * 256 * 4, stream);
  gap_sum_b<<<cdiv(N, 64), 256, 0, stream>>>(qpart, 256, batch, psum, N, 256, 64);
  head_k<<<64, 64, 0, stream>>>(psum, ginv, out_w, out_b, (float*)d_out);
}